// Round 9
// baseline (319.865 us; speedup 1.0000x reference)
//
#include <hip/hip_runtime.h>

// Multi-scale parabolic morphological closing — 2-dispatch fused 2D morphology.
// closing_k = ero2d(dil2d(x)), W_k = 4<<k, weight(d) = c*(4/W^2)*d^2.
// Each dispatch computes a full 2D dilation (or erosion) per 64x64 tile:
//   phase 1: vertical 8-output scans over a (64+2W)-wide column strip,
//            results into LDS [128][65] (stride 65: conflict-free both phases)
//   phase 2: horizontal 8-output scans from LDS, coalesced float4 stores.
// Candidate algebra: v -+ cw*(D-pp)^2 = (v -+ cw*D^2) +- (2cw*D)*pp -+ cw*pp^2,
// tap constants from anchors via exact fmas (t, t(t-1)/2 exact small ints ->
// bitwise-identical q,s to R7) -> absmax unchanged. Out-of-image taps get
// +-1e30 PAD (never wins vs ref's +-10000-weighted pad; absmax-verified R1-R8).
// R9 rationale: R3-R8 pinned at ~42us/stage with ALL pipes <30% (latency-bound
// at ~3.3 waves/SIMD vs 500-900cy L3/HBM latency). Levers: halve stage count
// (2 fused dispatches), LDS-source the H-scan, prefetch-pipeline the V-scan,
// raise occupancy (launch_bounds(512,6)).

#define HH 256
#define FAST 256
#define BC 32
#define NS 4
#define HW (HH * FAST)
#define SLICE ((long)BC * HW)
#define LSTR 65   // LDS col stride (floats); 65%4==1 -> 2-way max both phases

// 8-output scan over 2W+8 taps in nb = W/4+1 batches of 8, prefetch-pipelined.
// load(t) returns tap t's input value. Head batch: tap t valid for pp <= t;
// tail batch: valid for pp >= t-2W; middle: all. Epilogue folds -+cw*pp^2.
template <bool IS_MAX, class F>
__device__ __forceinline__ void scan8(F load, int nb, float q0, float qs0,
                                      float s0, float tw, float ss, float cw,
                                      float res[8])
{
    const float PAD = IS_MAX ? -1e30f : 1e30f;
    float acc[8];
#pragma unroll
    for (int pp = 0; pp < 8; ++pp) acc[pp] = PAD;

    float vA[8], vB[8];
#pragma unroll
    for (int j = 0; j < 8; ++j) vA[j] = load(j);

    for (int b = 0; b < nb; ++b) {
        if (b + 1 < nb) {
#pragma unroll
            for (int j = 0; j < 8; ++j) vB[j] = load(8 * (b + 1) + j);
        }
        const float tb = (float)(8 * b);
        if (b == 0) {
            // head: t = j, valid pp <= j
#pragma unroll
            for (int j = 0; j < 8; ++j) {
                const float tf = (float)j;
                const float q = fmaf(0.5f * tf * (tf - 1.0f), tw,
                                     fmaf(tf, qs0, q0));
                const float sv = fmaf(tf, ss, s0);
                const float vp = IS_MAX ? vA[j] - q : vA[j] + q;
#pragma unroll
                for (int pp = 0; pp < 8; ++pp)
                    if (pp <= j) {
                        const float cnd = fmaf(sv, (float)pp, vp);
                        acc[pp] = IS_MAX ? fmaxf(acc[pp], cnd)
                                         : fminf(acc[pp], cnd);
                    }
            }
        } else if (b == nb - 1) {
            // tail: t = 2W + j, valid pp >= j
#pragma unroll
            for (int j = 0; j < 8; ++j) {
                const float tf = tb + (float)j;
                const float q = fmaf(0.5f * tf * (tf - 1.0f), tw,
                                     fmaf(tf, qs0, q0));
                const float sv = fmaf(tf, ss, s0);
                const float vp = IS_MAX ? vA[j] - q : vA[j] + q;
#pragma unroll
                for (int pp = 0; pp < 8; ++pp)
                    if (pp >= j) {
                        const float cnd = fmaf(sv, (float)pp, vp);
                        acc[pp] = IS_MAX ? fmaxf(acc[pp], cnd)
                                         : fminf(acc[pp], cnd);
                    }
            }
        } else {
            // middle: all pp valid; pairs -> v_max3/v_min3
#pragma unroll
            for (int j = 0; j < 8; j += 2) {
                const float tf0 = tb + (float)j;
                const float tf1 = tb + (float)(j + 1);
                const float qa = fmaf(0.5f * tf0 * (tf0 - 1.0f), tw,
                                      fmaf(tf0, qs0, q0));
                const float qb = fmaf(0.5f * tf1 * (tf1 - 1.0f), tw,
                                      fmaf(tf1, qs0, q0));
                const float sa = fmaf(tf0, ss, s0);
                const float sb = fmaf(tf1, ss, s0);
                const float va = IS_MAX ? vA[j] - qa : vA[j] + qa;
                const float vb = IS_MAX ? vA[j + 1] - qb : vA[j + 1] + qb;
#pragma unroll
                for (int pp = 0; pp < 8; ++pp) {
                    const float ca = fmaf(sa, (float)pp, va);
                    const float cb = fmaf(sb, (float)pp, vb);
                    acc[pp] = IS_MAX ? fmaxf(acc[pp], fmaxf(ca, cb))
                                     : fminf(acc[pp], fminf(ca, cb));
                }
            }
        }
        if (b + 1 < nb) {
#pragma unroll
            for (int j = 0; j < 8; ++j) vA[j] = vB[j];
        }
    }
#pragma unroll
    for (int pp = 0; pp < 8; ++pp)
        res[pp] = IS_MAX ? fmaf(-cw, (float)(pp * pp), acc[pp])
                         : fmaf(cw, (float)(pp * pp), acc[pp]);
}

template <bool IS_MAX>
__global__ __launch_bounds__(512, 6) void morph2d(const float* __restrict__ in,
                                                  float* __restrict__ out,
                                                  const float* __restrict__ cptr,
                                                  long in_ks, long in_zs,
                                                  long out_ks, long out_zs,
                                                  int kofs)
{
    __shared__ float lds[128 * LSTR];
    const int k = kofs + (int)blockIdx.y;
    const int W = 4 << k;                    // 4,8,16,32 (block-uniform)
    const int width = 64 + 2 * W;            // phase-1 strip width <= 128
    const int nb = (W >> 2) + 1;             // tap batches of 8
    const float cw = ldexpf(cptr[0], -(2 + 2 * k));   // c*4/W^2, pow2-exact
    const float PAD = IS_MAX ? -1e30f : 1e30f;
    const float tw = 2.0f * cw;
    const float ss = IS_MAX ? tw : -tw;
    const float q0 = cw * (float)(W * W);
    const float qs0 = cw * (float)(1 - 2 * W);
    const float s0 = IS_MAX ? (-tw * (float)W) : (tw * (float)W);

    const int x0 = ((int)blockIdx.x & 3) * 64;
    const int h0 = ((int)blockIdx.x >> 2) * 64;
    const float* img = in + (long)k * in_ks + (long)blockIdx.z * in_zs;
    const bool colint = (x0 >= W) && (x0 + 63 + W < HH);

    // ---- phase 1: vertical scans of the (width x 64) strip into LDS ----
    for (int iter = 0; iter < 2; ++iter) {
        const int task = iter * 512 + (int)threadIdx.x;
        const int cc = task & 127;           // strip column
        const int g = task >> 7;             // 0..7 row group (wave-uniform)
        if (cc < width) {
            const int xc = x0 - W + cc;
            const int xcc = min(max(xc, 0), HH - 1);
            const bool colok = (xc == xcc);
            const float* pb = img + xcc;
            const int rowbase = h0 + 8 * g - W;
            float res[8];
            if (colint && rowbase >= 0 && rowbase + 2 * W + 7 < HH) {
                auto ld = [&](int t) { return pb[(rowbase + t) * FAST]; };
                scan8<IS_MAX>(ld, nb, q0, qs0, s0, tw, ss, cw, res);
            } else {
                auto ld = [&](int t) {
                    const int row = rowbase + t;
                    const int rc = min(max(row, 0), HH - 1);
                    const float v = pb[rc * FAST];
                    return (colok && row == rc) ? v : PAD;
                };
                scan8<IS_MAX>(ld, nb, q0, qs0, s0, tw, ss, cw, res);
            }
            float* lp = lds + cc * LSTR + 8 * g;
#pragma unroll
            for (int j = 0; j < 8; ++j) lp[j] = res[j];   // stride-65: no conflicts
        }
    }
    __syncthreads();

    // ---- phase 2: horizontal scans from LDS, coalesced stores ----
    const int cg = (int)threadIdx.x & 7;     // output col group (8 cols)
    const int r = (int)threadIdx.x >> 3;     // output row 0..63
    const float* lb = lds + (8 * cg) * LSTR + r;
    auto ld2 = [&](int t) { return lb[t * LSTR]; };
    float res[8];
    scan8<IS_MAX>(ld2, nb, q0, qs0, s0, tw, ss, cw, res);

    float* op = out + (long)k * out_ks + (long)blockIdx.z * out_zs
              + (long)(h0 + r) * FAST + (x0 + 8 * cg);
    *(float4*)(op)     = make_float4(res[0], res[1], res[2], res[3]);
    *(float4*)(op + 4) = make_float4(res[4], res[5], res[6], res[7]);
}

extern "C" void kernel_launch(void* const* d_in, const int* in_sizes, int n_in,
                              void* d_out, int out_size, void* d_ws, size_t ws_size,
                              hipStream_t stream)
{
    const float* x = (const float*)d_in[0];   // [4,8,256,256] fp32
    const float* c = (const float*)d_in[1];   // scalar se_coef
    float* out = (float*)d_out;               // [4,8,4,256,256] fp32
    float* ws  = (float*)d_ws;

    dim3 b(512);
    if (ws_size >= (size_t)(NS * SLICE) * sizeof(float)) {
        // 2 dispatches: dil2d (x -> ws, packed [k][z][HW]) then ero2d (ws -> out)
        dim3 g(16, NS, BC);
        morph2d<true ><<<g, b, 0, stream>>>(x,  ws,  c, 0,     HW, SLICE, HW, 0);
        morph2d<false><<<g, b, 0, stream>>>(ws, out, c, SLICE, HW, HW, (long)NS * HW, 0);
    } else {
        // fallback: per-scale, one 8.4MB ws slice
        dim3 g(16, 1, BC);
        for (int k = 0; k < NS; ++k) {
            morph2d<true ><<<g, b, 0, stream>>>(x,  ws,            c, 0, HW, 0, HW, k);
            morph2d<false><<<g, b, 0, stream>>>(ws, out + (long)k * HW, c, 0, HW, 0,
                                                (long)NS * HW, k);
        }
    }
}